// Round 1
// baseline (132.858 us; speedup 1.0000x reference)
//
#include <hip/hip_runtime.h>

// LePEAttention without softmax:  out = Q (K^T V) * (2*SCALE)
// Shapes: q,k,v (T=4, B=2, C=256, H=56, W=56) fp32.
// Windows: H_NUM=1, W_NUM=2 -> 2 windows of 56x28 (N=1568), heads=8, d=32.
// Problem index p in [0,128): p = ((t*B + b)*2 + win)*8 + head.

#define TDIM 4
#define BDIM 2
#define CDIM 256
#define HDIM 56
#define WDIM 56
#define DHEAD 32
#define WSP 28
#define NPOS 1568          // 56*28 positions per window
#define HW 3136            // 56*56
#define NPROB 128
#define SPLIT 4
#define NP_SPLIT 392       // NPOS / SPLIT
#define CHUNK 56
#define NCHUNK 7           // NP_SPLIT / CHUNK
#define LDSTRIDE 57        // 56 + 1 pad: conflict-free strided reads
#define SCALE2 0.35355339059327373f   // 2 * (32)^-0.5

// ---------------- Kernel 1: M[p] = K_p^T V_p  (32x32 per problem) ------------
__global__ __launch_bounds__(256) void kv_kernel(const float* __restrict__ K,
                                                 const float* __restrict__ V,
                                                 float* __restrict__ M) {
    __shared__ float kT[32 * LDSTRIDE];
    __shared__ float vT[32 * LDSTRIDE];
    __shared__ float red[4 * 1024];

    const int blk  = blockIdx.x;
    const int p    = blk >> 2;       // problem
    const int s    = blk & 3;        // N-split
    const int head = p & 7;
    const int win  = (p >> 3) & 1;
    const int b    = (p >> 4) & 1;
    const int t    = p >> 5;

    const long base = ((long)(t * BDIM + b) * CDIM + head * DHEAD) * HW;
    const float* __restrict__ Kb = K + base;
    const float* __restrict__ Vb = V + base;

    const int tid = threadIdx.x;
    const int l   = tid & 63;        // lane
    const int w   = tid >> 6;        // wave id (0..3)
    const int dd0 = (l >> 3) * 4;    // 8 dd-tiles
    const int de0 = (l & 7) * 4;     // 8 de-tiles

    float acc[4][4] = {};

    const int n_base = s * NP_SPLIT;
    for (int c = 0; c < NCHUNK; ++c) {
        const int n0 = n_base + c * CHUNK;
        // stage 32 channels x 56 positions of K and V (1792 = 7*256 elements each)
        #pragma unroll
        for (int jj = 0; jj < 7; ++jj) {
            const int idx = tid + 256 * jj;
            const int ch  = idx / 56;
            const int pp  = idx - ch * 56;
            const int n   = n0 + pp;
            const int y   = n / 28;
            const int x   = win * 28 + (n - y * 28);
            const int ga  = ch * HW + y * WDIM + x;
            kT[ch * LDSTRIDE + pp] = Kb[ga];
            vT[ch * LDSTRIDE + pp] = Vb[ga];
        }
        __syncthreads();
        // each wave handles 14 of the 56 staged positions
        const int pbeg = w * 14;
        for (int pp = pbeg; pp < pbeg + 14; ++pp) {
            float kv[4], vv[4];
            #pragma unroll
            for (int i = 0; i < 4; ++i) kv[i] = kT[(dd0 + i) * LDSTRIDE + pp];
            #pragma unroll
            for (int j = 0; j < 4; ++j) vv[j] = vT[(de0 + j) * LDSTRIDE + pp];
            #pragma unroll
            for (int i = 0; i < 4; ++i)
                #pragma unroll
                for (int j = 0; j < 4; ++j)
                    acc[i][j] += kv[i] * vv[j];
        }
        __syncthreads();
    }

    // reduce the 4 wave-copies of the 32x32 tile, then atomically add to M[p]
    #pragma unroll
    for (int i = 0; i < 4; ++i)
        #pragma unroll
        for (int j = 0; j < 4; ++j)
            red[w * 1024 + (dd0 + i) * 32 + (de0 + j)] = acc[i][j];
    __syncthreads();
    #pragma unroll
    for (int jj = 0; jj < 4; ++jj) {
        const int m = tid * 4 + jj;
        const float sum = red[m] + red[1024 + m] + red[2048 + m] + red[3072 + m];
        atomicAdd(&M[p * 1024 + m], sum);
    }
}

// ---------------- Kernel 2: out = Q * M[p] * SCALE2 -------------------------
__global__ __launch_bounds__(256) void qm_kernel(const float* __restrict__ Q,
                                                 const float* __restrict__ M,
                                                 float* __restrict__ Out) {
    const int blk = blockIdx.x;
    const int p   = blk / 7;            // uniform per block -> scalar M loads
    const int c   = blk - p * 7;
    const int n   = c * 256 + threadIdx.x;

    const int head = p & 7;
    const int win  = (p >> 3) & 1;
    const int b    = (p >> 4) & 1;
    const int t    = p >> 5;
    const float* __restrict__ Mp = M + p * 1024;

    if (n >= NPOS) return;

    const int y = n / 28;
    const int x = win * 28 + (n - y * 28);
    const long base = ((long)(t * BDIM + b) * CDIM + head * DHEAD) * HW
                    + y * WDIM + x;
    const float* __restrict__ Qb = Q + base;
    float* __restrict__ Ob = Out + base;

    float acc[32] = {};
    #pragma unroll 4
    for (int dd = 0; dd < 32; ++dd) {
        const float qv = Qb[dd * HW];
        #pragma unroll
        for (int de = 0; de < 32; ++de)
            acc[de] += qv * Mp[dd * 32 + de];
    }
    #pragma unroll
    for (int de = 0; de < 32; ++de)
        Ob[de * HW] = acc[de] * SCALE2;
}

extern "C" void kernel_launch(void* const* d_in, const int* in_sizes, int n_in,
                              void* d_out, int out_size, void* d_ws, size_t ws_size,
                              hipStream_t stream) {
    const float* q = (const float*)d_in[0];
    const float* k = (const float*)d_in[1];
    const float* v = (const float*)d_in[2];
    // d_in[3] is v_lamda == 1 (ignored)
    float* out = (float*)d_out;
    float* M   = (float*)d_ws;   // 128 * 32 * 32 floats = 512 KB

    hipMemsetAsync(M, 0, NPROB * 1024 * sizeof(float), stream);
    kv_kernel<<<NPROB * SPLIT, 256, 0, stream>>>(k, v, M);
    qm_kernel<<<NPROB * 7, 256, 0, stream>>>(q, M, out);
}

// Round 2
// 129.402 us; speedup vs baseline: 1.0267x; 1.0267x over previous
//
#include <hip/hip_runtime.h>

// LePEAttention without softmax:  out = Q (K^T V) * (2*SCALE)
// q,k,v: (T=4, B=2, C=256, H=56, W=56) fp32. Windows: 2 of 56x28 (N=1568),
// heads=8, d=32. 128 problems: p = ((t*2+b)*2+win)*8+head.
//
// Kernel 1 (kv): Mpart[p][s] = K_s^T V_s over 112-position split s (14 splits).
// Kernel 2 (qm): M = SCALE2 * sum_s Mpart[p][s];  out = Q * M.

#define HW 3136
#define WDIM 56
#define NPOS 1568
#define NPROB 128
#define SPLIT 14
#define PSPLIT 112            // positions per kv block
#define LROW 36               // LDS row stride (floats): 32 ch + 4 pad (16B-aligned rows)
#define SCALE2 0.35355339059327373f   // 2 * 32^-0.5

// ---------------- Kernel 1: partial K^T V ----------------------------------
__global__ __launch_bounds__(256) void kv_kernel(const float* __restrict__ K,
                                                 const float* __restrict__ V,
                                                 float* __restrict__ Mpart) {
    __shared__ float lds[2 * PSPLIT * LROW];   // kT | vT; overlaid as red[4][1024] later
    float* kT = lds;
    float* vT = lds + PSPLIT * LROW;

    const int blk = blockIdx.x;
    const int p   = blk / SPLIT;
    const int s   = blk - p * SPLIT;
    const int head = p & 7;
    const int win  = (p >> 3) & 1;
    const int b    = (p >> 4) & 1;
    const int t    = p >> 5;

    const size_t base = (size_t)((t * 2 + b) * 256 + head * 32) * HW;
    const float* __restrict__ Kb = K + base;
    const float* __restrict__ Vb = V + base;

    const int tid = threadIdx.x;

    // ---- stage 112 positions x 32 channels of K and V, transposed to [pos][ch]
    // 1792 items = 2 bufs x 8 ch-groups x 112 positions; 7 items/thread.
    #pragma unroll
    for (int j = 0; j < 7; ++j) {
        const int item = tid + 256 * j;
        const int isv  = item >= 896 ? 1 : 0;   // wave-uniform
        const int r    = item - isv * 896;
        const int chg  = r / 112;               // channel group 0..7
        const int pp   = r - chg * 112;         // position 0..111 (lane-consecutive)
        const int n  = s * PSPLIT + pp;
        const int y  = n / 28;
        const int x  = n - y * 28;
        const float* src = (isv ? Vb : Kb)
                         + (size_t)chg * 4 * HW + y * WDIM + win * 28 + x;
        float4 val;
        val.x = src[0];
        val.y = src[HW];
        val.z = src[2 * HW];
        val.w = src[3 * HW];
        float* dst = isv ? vT : kT;
        *(float4*)&dst[pp * LROW + chg * 4] = val;   // ds_write_b128
    }
    __syncthreads();

    // ---- rank-1 accumulation: lane owns 4x4 tile of the 32x32 output
    const int l   = tid & 63;
    const int w   = tid >> 6;
    const int dd0 = (l >> 3) * 4;
    const int de0 = (l & 7) * 4;

    float acc[4][4] = {{0.f}};
    const int p0 = w * 28;          // 28 positions per wave
    #pragma unroll 4
    for (int pp = p0; pp < p0 + 28; ++pp) {
        const float4 ka = *(const float4*)&kT[pp * LROW + dd0];  // ds_read_b128
        const float4 va = *(const float4*)&vT[pp * LROW + de0];  // ds_read_b128
        acc[0][0] += ka.x * va.x; acc[0][1] += ka.x * va.y;
        acc[0][2] += ka.x * va.z; acc[0][3] += ka.x * va.w;
        acc[1][0] += ka.y * va.x; acc[1][1] += ka.y * va.y;
        acc[1][2] += ka.y * va.z; acc[1][3] += ka.y * va.w;
        acc[2][0] += ka.z * va.x; acc[2][1] += ka.z * va.y;
        acc[2][2] += ka.z * va.z; acc[2][3] += ka.z * va.w;
        acc[3][0] += ka.w * va.x; acc[3][1] += ka.w * va.y;
        acc[3][2] += ka.w * va.z; acc[3][3] += ka.w * va.w;
    }
    __syncthreads();

    // ---- reduce the 4 wave copies (overlay lds[0..4095])
    #pragma unroll
    for (int i = 0; i < 4; ++i)
        #pragma unroll
        for (int jj = 0; jj < 4; ++jj)
            lds[w * 1024 + (dd0 + i) * 32 + (de0 + jj)] = acc[i][jj];
    __syncthreads();

    const float4 r0 = *(const float4*)&lds[tid * 4];
    const float4 r1 = *(const float4*)&lds[1024 + tid * 4];
    const float4 r2 = *(const float4*)&lds[2048 + tid * 4];
    const float4 r3 = *(const float4*)&lds[3072 + tid * 4];
    float4 o;
    o.x = r0.x + r1.x + r2.x + r3.x;
    o.y = r0.y + r1.y + r2.y + r3.y;
    o.z = r0.z + r1.z + r2.z + r3.z;
    o.w = r0.w + r1.w + r2.w + r3.w;
    *(float4*)&Mpart[(size_t)blk * 1024 + tid * 4] = o;
}

// ---------------- Kernel 2: out = Q * (SCALE2 * sum_s Mpart) ----------------
__global__ __launch_bounds__(256) void qm_kernel(const float* __restrict__ Q,
                                                 const float* __restrict__ Mpart,
                                                 float* __restrict__ Out) {
    __shared__ float M[1024];
    const int blk = blockIdx.x;
    const int p   = blk / 7;
    const int c   = blk - p * 7;
    const int tid = threadIdx.x;

    // sum the 14 partials; fold in the scale
    const float* mp = Mpart + (size_t)p * SPLIT * 1024 + tid * 4;
    float4 sum = {0.f, 0.f, 0.f, 0.f};
    #pragma unroll
    for (int s = 0; s < SPLIT; ++s) {
        const float4 v = *(const float4*)&mp[s * 1024];
        sum.x += v.x; sum.y += v.y; sum.z += v.z; sum.w += v.w;
    }
    sum.x *= SCALE2; sum.y *= SCALE2; sum.z *= SCALE2; sum.w *= SCALE2;
    *(float4*)&M[tid * 4] = sum;
    __syncthreads();

    const int head = p & 7;
    const int win  = (p >> 3) & 1;
    const int b    = (p >> 4) & 1;
    const int t    = p >> 5;

    if (tid < 224) {
        const int n = c * 224 + tid;              // 7 blocks x 224 = 1568
        const int y = n / 28;
        const int x = n - y * 28;
        const size_t base = (size_t)((t * 2 + b) * 256 + head * 32) * HW
                          + y * WDIM + win * 28 + x;
        const float* __restrict__ Qb = Q + base;
        float* __restrict__ Ob = Out + base;

        float acc[32] = {0.f};
        #pragma unroll 8
        for (int dd = 0; dd < 32; ++dd) {
            const float qv = Qb[(size_t)dd * HW];
            #pragma unroll
            for (int g = 0; g < 8; ++g) {
                const float4 m = *(const float4*)&M[dd * 32 + g * 4];  // broadcast b128
                acc[g * 4 + 0] += qv * m.x;
                acc[g * 4 + 1] += qv * m.y;
                acc[g * 4 + 2] += qv * m.z;
                acc[g * 4 + 3] += qv * m.w;
            }
        }
        #pragma unroll
        for (int de = 0; de < 32; ++de)
            Ob[(size_t)de * HW] = acc[de];
    }
}

extern "C" void kernel_launch(void* const* d_in, const int* in_sizes, int n_in,
                              void* d_out, int out_size, void* d_ws, size_t ws_size,
                              hipStream_t stream) {
    const float* q = (const float*)d_in[0];
    const float* k = (const float*)d_in[1];
    const float* v = (const float*)d_in[2];
    // d_in[3] is v_lamda == 1 (ignored)
    float* out   = (float*)d_out;
    float* Mpart = (float*)d_ws;   // 128*14*1024 floats = 7.34 MB, fully written by kv

    kv_kernel<<<NPROB * SPLIT, 256, 0, stream>>>(k, v, Mpart);
    qm_kernel<<<NPROB * 7, 256, 0, stream>>>(q, Mpart, out);
}